// Round 7
// baseline (50.498 us; speedup 1.0000x reference)
//
#include <hip/hip_runtime.h>

typedef unsigned short u16;
typedef unsigned int u32;
typedef __attribute__((ext_vector_type(2))) unsigned int u32x2;
typedef __attribute__((ext_vector_type(8))) short bf16x8;
typedef __attribute__((ext_vector_type(4))) float f32x4;

#define CIN 128
#define OC 128
#define NP 1024      // 32*32 spatial
#define KTOT 1152    // 9*128, k = rs*128 + c
#define NSTEP 18
#define BK 64

__device__ __forceinline__ u16 f2bf(float f) {
  unsigned b = __builtin_bit_cast(unsigned, f);
  b += 0x7fffu + ((b >> 16) & 1u);   // RNE; inputs are finite
  return (u16)(b >> 16);
}

// w[i][oc][c][r][s] f32  ->  wbf[i][oc][rs][c] bf16   (k = rs*128 + c)
__global__ void wcvt_kernel(const float* __restrict__ w, u16* __restrict__ wbf) {
  __shared__ u16 lds[KTOT];
  const int blk = blockIdx.x;        // i*128 + oc
  const int t = threadIdx.x;         // 0..127
  const float* src = w + (size_t)blk * KTOT;
  u16* dst = wbf + (size_t)blk * KTOT;
#pragma unroll
  for (int e = 0; e < 9; ++e) {
    int idx = t + 128 * e;           // coalesced read
    lds[idx] = f2bf(src[idx]);       // lds[c*9+rs] layout (input order)
  }
  __syncthreads();
#pragma unroll
  for (int e = 0; e < 9; ++e) {
    int o = t + 128 * e;             // o = rs*128 + c ; rs=e, c=t
    dst[o] = lds[t * 9 + e];         // coalesced write
  }
}

// Xs: 4 rows x 34 cols x 128 ch bf16, stored as 16B slots with XOR swizzle:
//   slot'(cslot, col) = cslot ^ (col & 7);  u16 index = ((r*34+col)*16 + slot')*8 + (c&7)
// K-loop is barrier-free: A comes straight from L2, Xs is read-only.
__global__ __launch_bounds__(256, 2) void conv_mfma(
    const float* __restrict__ x,     // [32][128][32][32] f32
    const u16* __restrict__ wbf,     // [32][128][1152] bf16
    const float* __restrict__ bias,  // [32][1][128]
    float* __restrict__ out) {       // [32][1][128][32][32]
  __shared__ u16 Xs[4 * 34 * 128];   // 34,816 B; only LDS in this kernel

  // flat grid 512 = 8 XCDs x 64; bijective XCD swizzle -> 4 samples per XCD
  const int wg = (int)blockIdx.x;
  const int swz = (wg & 7) * 64 + (wg >> 3);
  const int i  = swz >> 4;
  const int pt = swz & 15;
  const int p0 = pt * 64;           // 64 pixels = image rows {2pt, 2pt+1}
  const int tid = (int)threadIdx.x;
  const int lane = tid & 63;
  const int wid = tid >> 6;
  const int wm = wid >> 1;           // wave tile: 64 oc x 32 p
  const int wn = wid & 1;

  const float* xi = x + (size_t)i * CIN * NP;
  const u16*   wi = wbf + (size_t)i * OC * KTOT;

  const int lhi = lane >> 4;         // k-subslot 0..3
  // A direct-load base: lane covers row wm*64 + mi*16 + (lane&15), k-chunk lhi*8
  const u16* agbase = wi + (size_t)(wm * 64 + (lane & 15)) * KTOT + lhi * 8;

#define LOADG(dst, step) do {                                   \
    const u16* _g = agbase + (step) * BK;                       \
    _Pragma("unroll")                                           \
    for (int _kk = 0; _kk < 2; ++_kk)                           \
      _Pragma("unroll")                                         \
      for (int _mi = 0; _mi < 4; ++_mi)                         \
        dst[_kk * 4 + _mi] =                                    \
            *(const bf16x8*)(_g + _mi * 16 * KTOT + _kk * 32);  \
  } while (0)

  bf16x8 a_cur[8], a_nxt[8];
  LOADG(a_cur, 0);                   // in flight during x-stage

  // ---------- one-time x-stage: rows yr = 2pt-1 .. 2pt+2 ----------
  {
    const int xx = tid & 31;         // image col 0..31 -> LDS col xx+1
    const int cg = tid >> 5;         // channel group 0..7 (16 ch each)
    const int col = xx + 1;
    const int csw = col & 7;
#pragma unroll
    for (int r = 0; r < 4; ++r) {
      const int yr = 2 * pt - 1 + r;
      float v[16];
      if ((unsigned)yr < 32u) {
        const float* src = xi + (size_t)(cg * 16) * NP + yr * 32 + xx;
#pragma unroll
        for (int j = 0; j < 16; ++j) v[j] = src[(size_t)j * NP];
      } else {
#pragma unroll
        for (int j = 0; j < 16; ++j) v[j] = 0.f;
      }
      u32 pk[8];
#pragma unroll
      for (int m = 0; m < 8; ++m)
        pk[m] = (u32)f2bf(v[2 * m]) | ((u32)f2bf(v[2 * m + 1]) << 16);
      // 4x 8B writes: q covers channels cg*16 + 4q .. +3
#pragma unroll
      for (int q = 0; q < 4; ++q) {
        const int cslot = cg * 2 + (q >> 1);
        const int idx = ((r * 34 + col) * 16 + (cslot ^ csw)) * 8 + (q & 1) * 4;
        *(u32x2*)(&Xs[idx]) = (u32x2){pk[2 * q], pk[2 * q + 1]};
      }
    }
    // column halo (col 0 and 33): zeros, 4 rows x 2 cols x 16 slots
    if (tid < 128) {
      const int r = tid >> 5;
      const int hc = ((tid >> 4) & 1) ? 33 : 0;
      const int s = tid & 15;
      const int idx = ((r * 34 + hc) * 16 + (s ^ (hc & 7))) * 8;
      *(bf16x8*)(&Xs[idx]) = (bf16x8){0, 0, 0, 0, 0, 0, 0, 0};
    }
  }

  f32x4 acc[4][2];
#pragma unroll
  for (int mi = 0; mi < 4; ++mi)
#pragma unroll
    for (int ni = 0; ni < 2; ++ni)
      acc[mi][ni] = (f32x4){0.f, 0.f, 0.f, 0.f};

  // per-lane B-read constants: pixel p_local = wn*32 + ni*16 + (lane&15)
  const int cb0 = (lane & 15) + 1;         // ni=0 LDS col before dx

  __syncthreads();                   // Xs visible; the ONLY block-wide barrier

#pragma unroll
  for (int step = 0; step < NSTEP; ++step) {
    const int rs = step >> 1;
    const int r3 = rs / 3;
    const int dy = r3 - 1;
    const int dx = (rs - r3 * 3) - 1;
    const int c0s = (step & 1) * 8;        // channel-slot base (64ch/8)
    const int rw = (wn + 1 + dy) * 34;     // x-stage row base (in cols)

    // prefetch next step's A fragments from L2 (no barrier to cross)
    if (step + 1 < NSTEP) LOADG(a_nxt, step + 1);

    // ---- math: 16 MFMAs per wave per K-step ----
    __builtin_amdgcn_s_setprio(1);
#pragma unroll
    for (int kkk = 0; kkk < 2; ++kkk) {
      bf16x8 bfr[2];
#pragma unroll
      for (int ni = 0; ni < 2; ++ni) {
        const int col = cb0 + ni * 16 + dx;
        const int cslot = c0s + kkk * 4 + lhi;
        const int idx = ((rw + col) * 16 + (cslot ^ (col & 7))) * 8;
        bfr[ni] = *(const bf16x8*)(&Xs[idx]);
      }
#pragma unroll
      for (int mi = 0; mi < 4; ++mi)
#pragma unroll
        for (int ni = 0; ni < 2; ++ni)
          acc[mi][ni] = __builtin_amdgcn_mfma_f32_16x16x32_bf16(
              a_cur[kkk * 4 + mi], bfr[ni], acc[mi][ni], 0, 0, 0);
    }
    __builtin_amdgcn_s_setprio(0);

    // rotate prefetch registers (full unroll -> copy-propagated away)
    if (step + 1 < NSTEP) {
#pragma unroll
      for (int e = 0; e < 8; ++e) a_cur[e] = a_nxt[e];
    }
  }

  // ---- epilogue (proven): C/D col=lane&15, row=(lane>>4)*4+j ----
  const int row0 = (lane >> 4) * 4;
  const int coln = lane & 15;
#pragma unroll
  for (int mi = 0; mi < 4; ++mi) {
    int oc = wm * 64 + mi * 16 + row0;
#pragma unroll
    for (int jj = 0; jj < 4; ++jj) {
      float bv = bias[i * OC + oc + jj];
      float* orow = out + ((size_t)i * OC + oc + jj) * NP;
#pragma unroll
      for (int ni = 0; ni < 2; ++ni) {
        int pg = p0 + wn * 32 + ni * 16 + coln;
        orow[pg] = acc[mi][ni][jj] + bv;
      }
    }
  }
#undef LOADG
}

extern "C" void kernel_launch(void* const* d_in, const int* in_sizes, int n_in,
                              void* d_out, int out_size, void* d_ws, size_t ws_size,
                              hipStream_t stream) {
  const float* x    = (const float*)d_in[0];
  const float* w    = (const float*)d_in[1];
  const float* bias = (const float*)d_in[2];
  float* out = (float*)d_out;
  u16* wbf = (u16*)d_ws;   // 32*128*1152 u16 = 9.44 MB

  wcvt_kernel<<<dim3(32 * OC), dim3(128), 0, stream>>>(w, wbf);
  conv_mfma<<<dim3(512), dim3(256), 0, stream>>>(x, wbf, bias, out);
}

// Round 8
// 30.109 us; speedup vs baseline: 1.6772x; 1.6772x over previous
//
#include <hip/hip_runtime.h>

typedef unsigned short u16;
typedef unsigned int u32;
typedef __attribute__((ext_vector_type(2))) unsigned int u32x2;
typedef __attribute__((ext_vector_type(8))) short bf16x8;
typedef __attribute__((ext_vector_type(4))) float f32x4;

#define CIN 128
#define OC 128
#define NP 1024      // 32*32 spatial
#define KTOT 1152    // 9*128, k = rs*128 + c
#define NSTEP 18
#define BK 64

__device__ __forceinline__ u16 f2bf(float f) {
  unsigned b = __builtin_bit_cast(unsigned, f);
  b += 0x7fffu + ((b >> 16) & 1u);   // RNE; inputs are finite
  return (u16)(b >> 16);
}

// w[i][oc][c][r][s] f32  ->  wbf[i][oc][rs][c] bf16   (k = rs*128 + c)
__global__ void wcvt_kernel(const float* __restrict__ w, u16* __restrict__ wbf) {
  __shared__ u16 lds[KTOT];
  const int blk = blockIdx.x;        // i*128 + oc
  const int t = threadIdx.x;         // 0..127
  const float* src = w + (size_t)blk * KTOT;
  u16* dst = wbf + (size_t)blk * KTOT;
#pragma unroll
  for (int e = 0; e < 9; ++e) {
    int idx = t + 128 * e;           // coalesced read
    lds[idx] = f2bf(src[idx]);       // lds[c*9+rs] layout (input order)
  }
  __syncthreads();
#pragma unroll
  for (int e = 0; e < 9; ++e) {
    int o = t + 128 * e;             // o = rs*128 + c ; rs=e, c=t
    dst[o] = lds[t * 9 + e];         // coalesced write
  }
}

// Xs: 6 rows x 34 cols x 128 ch bf16, 16B slots, XOR swizzle:
//   slot'(cslot, col) = cslot ^ (col & 7);  u16 idx = ((r*34+col)*16 + slot')*8 + (c&7)
// Asw: double-buffered 128oc x 64k tile, XOR-swizzled 128B rows (r6-proven).
// LDS total = 52,224 + 32,768 = 84,992 B -> 1 block/CU, 4 waves.
__global__ __launch_bounds__(256, 1) void conv_mfma(
    const float* __restrict__ x,     // [32][128][32][32] f32
    const u16* __restrict__ wbf,     // [32][128][1152] bf16
    const float* __restrict__ bias,  // [32][1][128]
    float* __restrict__ out) {       // [32][1][128][32][32]
  __shared__ u16 Xs[6 * 34 * 128];
  __shared__ u16 Asw[2][OC * BK];

  // grid 256 = 8 XCDs x 32; bijective XCD swizzle -> 4 samples per XCD
  const int wg = (int)blockIdx.x;
  const int swz = (wg & 7) * 32 + (wg >> 3);
  const int i  = swz >> 3;           // sample 0..31
  const int pt = swz & 7;            // pixel tile 0..7
  const int p0 = pt * 128;           // 128 pixels = image rows 4pt..4pt+3
  const int tid = (int)threadIdx.x;
  const int lane = tid & 63;
  const int wid = tid >> 6;
  const int wm = wid >> 1;           // oc half (64 oc)
  const int wn = wid & 1;            // pixel half (64 px = 2 image rows)

  const float* xi = x + (size_t)i * CIN * NP;
  const u16*   wi = wbf + (size_t)i * OC * KTOT;

  // A staging mapping (r6-proven): thread -> (oc row, k-half of 32)
  const int arow = tid >> 1;         // 0..127
  const int kh = tid & 1;
  const u16* abase = wi + arow * KTOT + kh * 32;

  bf16x8 ar[4];

#define LOADA(step) do {                                        \
    const u16* _a = abase + (step) * BK;                        \
    _Pragma("unroll")                                           \
    for (int e = 0; e < 4; ++e) ar[e] = *(const bf16x8*)(_a + e * 8); \
  } while (0)

#define STOREA(buf) do {                                        \
    _Pragma("unroll")                                           \
    for (int e = 0; e < 4; ++e) {                               \
      int _slot = (kh * 4 + e) ^ (arow & 7);                    \
      *(bf16x8*)(&Asw[buf][arow * BK + _slot * 8]) = ar[e];     \
    }                                                           \
  } while (0)

  LOADA(0);                          // in flight during x-stage

  // ---------- one-time x-stage: rows yr = 4pt-1 .. 4pt+4 (6 rows) ----------
  {
    const int xx = tid & 31;         // image col 0..31 -> LDS col xx+1
    const int cg = tid >> 5;         // channel group 0..7 (16 ch each)
    const int col = xx + 1;
    const int csw = col & 7;
#pragma unroll
    for (int r = 0; r < 6; ++r) {
      const int yr = 4 * pt - 1 + r;
      float v[16];
      if ((unsigned)yr < 32u) {
        const float* src = xi + (size_t)(cg * 16) * NP + yr * 32 + xx;
#pragma unroll
        for (int j = 0; j < 16; ++j) v[j] = src[(size_t)j * NP];
      } else {
#pragma unroll
        for (int j = 0; j < 16; ++j) v[j] = 0.f;
      }
      u32 pk[8];
#pragma unroll
      for (int m = 0; m < 8; ++m)
        pk[m] = (u32)f2bf(v[2 * m]) | ((u32)f2bf(v[2 * m + 1]) << 16);
#pragma unroll
      for (int q = 0; q < 4; ++q) {
        const int cslot = cg * 2 + (q >> 1);
        const int idx = ((r * 34 + col) * 16 + (cslot ^ csw)) * 8 + (q & 1) * 4;
        *(u32x2*)(&Xs[idx]) = (u32x2){pk[2 * q], pk[2 * q + 1]};
      }
    }
    // column halo (col 0 and 33): zeros, 6 rows x 2 cols x 16 slots = 192
    if (tid < 192) {
      const int r = tid / 32;
      const int hc = ((tid >> 4) & 1) ? 33 : 0;
      const int s = tid & 15;
      const int idx = ((r * 34 + hc) * 16 + (s ^ (hc & 7))) * 8;
      *(bf16x8*)(&Xs[idx]) = (bf16x8){0, 0, 0, 0, 0, 0, 0, 0};
    }
  }

  f32x4 acc[4][4];
#pragma unroll
  for (int mi = 0; mi < 4; ++mi)
#pragma unroll
    for (int ni = 0; ni < 4; ++ni)
      acc[mi][ni] = (f32x4){0.f, 0.f, 0.f, 0.f};

  const int lcol = lane & 15;
  const int lhi  = lane >> 4;        // k-subslot 0..3

  STOREA(0);
  __syncthreads();

#pragma unroll
  for (int step = 0; step < NSTEP; ++step) {
    const int cur = step & 1;
    const int rs = step >> 1;
    const int r3 = rs / 3;
    const int dy = r3 - 1;
    const int dx = (rs - r3 * 3) - 1;
    const int c0s = (step & 1) * 8;  // channel-slot base (64ch/8)

    // prefetch next A-tile into registers (16 VGPR; survives the barrier)
    if (step + 1 < NSTEP) LOADA(step + 1);

    // ---- math: 32 MFMAs per wave per K-step ----
    __builtin_amdgcn_s_setprio(1);
#pragma unroll
    for (int kkk = 0; kkk < 2; ++kkk) {
      bf16x8 af[4], bfr[4];
#pragma unroll
      for (int mi = 0; mi < 4; ++mi) {
        int row = wm * 64 + mi * 16 + lcol;
        int slot = (kkk * 4 + lhi) ^ (row & 7);
        af[mi] = *(const bf16x8*)(&Asw[cur][row * BK + slot * 8]);
      }
#pragma unroll
      for (int ni = 0; ni < 4; ++ni) {
        const int srow = wn * 2 + (ni >> 1) + 1 + dy;   // staged row
        const int col  = (ni & 1) * 16 + lcol + 1 + dx; // staged col
        const int cslot = c0s + kkk * 4 + lhi;
        const int idx = ((srow * 34 + col) * 16 + (cslot ^ (col & 7))) * 8;
        bfr[ni] = *(const bf16x8*)(&Xs[idx]);
      }
#pragma unroll
      for (int mi = 0; mi < 4; ++mi)
#pragma unroll
        for (int ni = 0; ni < 4; ++ni)
          acc[mi][ni] = __builtin_amdgcn_mfma_f32_16x16x32_bf16(
              af[mi], bfr[ni], acc[mi][ni], 0, 0, 0);
    }
    __builtin_amdgcn_s_setprio(0);

    // write next A-tile to the other buffer; WAR vs step-1 reads is
    // protected by the barrier at the end of step-1. One barrier/step.
    if (step + 1 < NSTEP) {
      STOREA(cur ^ 1);
      __syncthreads();
    }
  }

  // ---- epilogue (proven): C/D col=lane&15, row=(lane>>4)*4+j ----
  const int row0 = (lane >> 4) * 4;
#pragma unroll
  for (int mi = 0; mi < 4; ++mi) {
    int oc = wm * 64 + mi * 16 + row0;
#pragma unroll
    for (int jj = 0; jj < 4; ++jj) {
      float bv = bias[i * OC + oc + jj];
      float* orow = out + ((size_t)i * OC + oc + jj) * NP;
#pragma unroll
      for (int ni = 0; ni < 4; ++ni) {
        int pg = p0 + wn * 64 + ni * 16 + lcol;
        orow[pg] = acc[mi][ni][jj] + bv;
      }
    }
  }
#undef LOADA
#undef STOREA
}

extern "C" void kernel_launch(void* const* d_in, const int* in_sizes, int n_in,
                              void* d_out, int out_size, void* d_ws, size_t ws_size,
                              hipStream_t stream) {
  const float* x    = (const float*)d_in[0];
  const float* w    = (const float*)d_in[1];
  const float* bias = (const float*)d_in[2];
  float* out = (float*)d_out;
  u16* wbf = (u16*)d_ws;   // 32*128*1152 u16 = 9.44 MB

  wcvt_kernel<<<dim3(32 * OC), dim3(128), 0, stream>>>(w, wbf);
  conv_mfma<<<dim3(256), dim3(256), 0, stream>>>(x, wbf, bias, out);
}